// Round 7
// baseline (66.781 us; speedup 1.0000x reference)
//
#include <hip/hip_runtime.h>

typedef float f32x16 __attribute__((ext_vector_type(16)));
typedef short s16x8  __attribute__((ext_vector_type(8)));

#define B_SZ 4096
#define C_N  64
#define D_K  512
#define H_N  1024
#define MF   2            // 2 m-frags of 32 rows = 64-row chunk per block
#define TSTEPS 32         // 512 / 16
#define ZP_OFF_BYTES 32768
#define ZP_ROWS (B_SZ + 128)   // padded so unconditional frag loads stay in-bounds

__device__ __forceinline__ short f2bf(float f){
  unsigned u = __float_as_uint(f);
  u += 0x7FFFu + ((u >> 16) & 1u);   // RTNE
  return (short)(u >> 16);
}
// A&S 7.1.26, |err| <= 1.5e-7
__device__ __forceinline__ float erf_fast(float x){
  float ax = fabsf(x);
  float t = __builtin_amdgcn_rcpf(1.0f + 0.3275911f * ax);
  float p = t * (0.254829592f + t * (-0.284496736f + t * (1.421413741f +
            t * (-1.453152027f + t * 1.061405429f))));
  float r = 1.0f - p * __expf(-ax * ax);
  return copysignf(r, x);
}
__device__ __forceinline__ float gelu_exact(float x){
  return 0.5f * x * (1.0f + erf_fast(x * 0.70710678118654752f));
}

// Fused count + scan + scatter + out-init. One block of 1024.
__global__ void k_prep(const int* __restrict__ cid, const float* __restrict__ b2,
                       int* __restrict__ offsets, int* __restrict__ bucket,
                       float* __restrict__ out){
  __shared__ int hist[C_N];
  const int tid = threadIdx.x;
  if (tid < C_N) hist[tid] = 0;
  __syncthreads();
  for (int i = tid; i < B_SZ; i += 1024) atomicAdd(&hist[cid[i]], 1);
  __syncthreads();
  if (tid < 64){
    int v = hist[tid];
    int x = v;
    #pragma unroll
    for (int d = 1; d < 64; d <<= 1){
      int y = __shfl_up(x, d, 64);
      if (tid >= d) x += y;
    }
    offsets[tid] = x - v;
    if (tid == 63) offsets[64] = x;
    hist[tid] = x - v;                  // reuse as cursor
  }
  __syncthreads();
  for (int i = tid; i < B_SZ; i += 1024){
    int c = cid[i];
    int p = atomicAdd(&hist[c], 1);
    bucket[p] = i;
    out[i] = b2[c];
  }
}

// Pack z into bucket-ordered bf16 rows: zp[slot][0..511]. ~4 MB, L2/L3-resident.
__global__ void k_zpack(const float* __restrict__ z, const int* __restrict__ bucket,
                        short* __restrict__ zp){
  int u = blockIdx.x * 256 + threadIdx.x;     // 262144 units of 8 elems
  int slot = u >> 6;
  int k0 = (u & 63) * 8;
  const float* src = z + (size_t)bucket[slot] * D_K + k0;
  float4 a = *(const float4*)src;
  float4 b = *(const float4*)(src + 4);
  s16x8 v;
  v[0]=f2bf(a.x); v[1]=f2bf(a.y); v[2]=f2bf(a.z); v[3]=f2bf(a.w);
  v[4]=f2bf(b.x); v[5]=f2bf(b.y); v[6]=f2bf(b.z); v[7]=f2bf(b.w);
  *(s16x8*)(zp + ((size_t)slot << 9) + k0) = v;
}

__global__ __launch_bounds__(256, 3) void k_main(
    const short* __restrict__ zp, const float* __restrict__ W1,
    const float* __restrict__ b1, const float* __restrict__ W2,
    const int* __restrict__ offsets, const int* __restrict__ bucket,
    float* __restrict__ out)
{
  __shared__ float partial[64];
  // flat&63 = c  -> a company's 16 blocks share an XCD (zp/W1 L2 locality)
  const int flat = blockIdx.x;
  const int c = flat & 63;
  const int o = flat >> 6;                   // 0..15
  const int hs = o & 7, mc = o >> 3;         // 8 h-slices x 2 m-chunks
  const int off_c = offsets[c];
  const int n_c = offsets[c + 1] - off_c;
  const int rb = mc * 64;
  if (rb >= n_c) return;

  const int tid  = threadIdx.x;
  const int lane = tid & 63, wave = tid >> 6;      // 4 waves x 32 h
  const int l31 = lane & 31, lhi = lane >> 5;
  const int hcol = hs * 128 + wave * 32 + l31;     // h within company
  const float* Wc = W1 + (size_t)c * D_K * H_N + hcol;   // + k*1024
  const float b1v = b1[c * H_N + hcol];
  const float w2v = W2[c * H_N + hcol];

  if (tid < 64) partial[tid] = 0.0f;

  // per-m-frag A base: rows rb+m*32+l31, one addr + immediate k-offsets (t*32 B)
  const short* zbase0 = zp + ((size_t)(off_c + rb +      l31) << 9) + lhi * 8;
  const short* zbase1 = zp + ((size_t)(off_c + rb + 32 + l31) << 9) + lhi * 8;

  // ---- prologue: af 2-deep (k-steps 0,1), fb 4-deep (k-steps 0..3) ----
  s16x8 af[2][MF];
  af[0][0] = *(const s16x8*)(zbase0);
  af[0][1] = *(const s16x8*)(zbase1);
  af[1][0] = *(const s16x8*)(zbase0 + 16);
  af[1][1] = *(const s16x8*)(zbase1 + 16);

  float fb[4][8];
  #pragma unroll
  for (int s = 0; s < 4; ++s){
    #pragma unroll
    for (int e = 0; e < 8; ++e)
      fb[s][e] = Wc[(size_t)(s * 16 + lhi * 8 + e) * H_N];
  }

  f32x16 acc[MF];
  acc[0] = 0; acc[1] = 0;

  // ---- barrier-free K loop, fully unrolled: use -> mfma -> af(t+2) -> fb(t+4) ----
  #pragma unroll
  for (int t = 0; t < TSTEPS; ++t){
    s16x8 bf;
    #pragma unroll
    for (int e = 0; e < 8; ++e) bf[e] = f2bf(fb[t & 3][e]);
    acc[0] = __builtin_amdgcn_mfma_f32_32x32x16_bf16(af[t & 1][0], bf, acc[0], 0, 0, 0);
    acc[1] = __builtin_amdgcn_mfma_f32_32x32x16_bf16(af[t & 1][1], bf, acc[1], 0, 0, 0);
    if (t + 2 < TSTEPS){               // af slot free after use; 2-iter slack
      af[t & 1][0] = *(const s16x8*)(zbase0 + (t + 2) * 16);
      af[t & 1][1] = *(const s16x8*)(zbase1 + (t + 2) * 16);
    }
    if (t + 4 < TSTEPS){               // fb refill; 3-iter slack after wait-for-af
      #pragma unroll
      for (int e = 0; e < 8; ++e)
        fb[t & 3][e] = Wc[(size_t)((t + 4) * 16 + lhi * 8 + e) * H_N];
    }
  }

  // ---- epilogue: GELU + W2 dot, 32-lane reduce, LDS partial, flush ----
  __syncthreads();   // partial[] init visible
  #pragma unroll
  for (int m = 0; m < MF; ++m){
    #pragma unroll
    for (int r = 0; r < 16; ++r){
      int r_loc = m * 32 + (r & 3) + 8 * (r >> 2) + 4 * lhi;
      float s = gelu_exact(acc[m][r] + b1v) * w2v;
      s += __shfl_xor(s, 1, 64);
      s += __shfl_xor(s, 2, 64);
      s += __shfl_xor(s, 4, 64);
      s += __shfl_xor(s, 8, 64);
      s += __shfl_xor(s, 16, 64);
      if (l31 == 0 && rb + r_loc < n_c)
        atomicAdd(&partial[r_loc], s);
    }
  }
  __syncthreads();
  if (tid < 64){
    int g = rb + tid;
    if (g < n_c)
      atomicAdd(&out[bucket[off_c + g]], partial[tid]);
  }
}

extern "C" void kernel_launch(void* const* d_in, const int* in_sizes, int n_in,
                              void* d_out, int out_size, void* d_ws, size_t ws_size,
                              hipStream_t stream){
  const float* z  = (const float*)d_in[0];
  const int*   cid= (const int*)  d_in[1];
  const float* W1 = (const float*)d_in[2];
  const float* b1 = (const float*)d_in[3];
  const float* W2 = (const float*)d_in[4];
  const float* b2 = (const float*)d_in[5];
  float* out = (float*)d_out;

  int*   ws      = (int*)d_ws;
  int*   offsets = ws;                                   // [65]
  int*   bucket  = ws + 128;                             // [4096]
  short* zp      = (short*)((char*)d_ws + ZP_OFF_BYTES); // [ZP_ROWS*512] bf16

  k_prep <<<1, 1024, 0, stream>>>(cid, b2, offsets, bucket, out);
  k_zpack<<<1024, 256, 0, stream>>>(z, bucket, zp);
  k_main <<<C_N * 16, 256, 0, stream>>>(zp, W1, b1, W2, offsets, bucket, out);
}

// Round 8
// 61.564 us; speedup vs baseline: 1.0847x; 1.0847x over previous
//
#include <hip/hip_runtime.h>

typedef float f32x16 __attribute__((ext_vector_type(16)));
typedef short s16x8  __attribute__((ext_vector_type(8)));

#define B_SZ 4096
#define C_N  64
#define D_K  512
#define H_N  1024
#define BK   16                 // k per tile
#define NT   32                 // 512/16 tiles
#define ROWS 32                 // rows per block (one 32x32 m-frag)
#define ZP_OFF_BYTES 32768
#define ZP_ROWS (B_SZ + 128)    // pad: off_c+rb+31 <= 4096+96+31 = 4223 < 4224

__device__ __forceinline__ short f2bf(float f){
  unsigned u = __float_as_uint(f);
  u += 0x7FFFu + ((u >> 16) & 1u);   // RTNE
  return (short)(u >> 16);
}
// A&S 7.1.26, |err| <= 1.5e-7
__device__ __forceinline__ float erf_fast(float x){
  float ax = fabsf(x);
  float t = __builtin_amdgcn_rcpf(1.0f + 0.3275911f * ax);
  float p = t * (0.254829592f + t * (-0.284496736f + t * (1.421413741f +
            t * (-1.453152027f + t * 1.061405429f))));
  float r = 1.0f - p * __expf(-ax * ax);
  return copysignf(r, x);
}
__device__ __forceinline__ float gelu_exact(float x){
  return 0.5f * x * (1.0f + erf_fast(x * 0.70710678118654752f));
}

// Fused count + scan + scatter + out-init. One block of 1024.
__global__ void k_prep(const int* __restrict__ cid, const float* __restrict__ b2,
                       int* __restrict__ offsets, int* __restrict__ bucket,
                       float* __restrict__ out){
  __shared__ int hist[C_N];
  const int tid = threadIdx.x;
  if (tid < C_N) hist[tid] = 0;
  __syncthreads();
  for (int i = tid; i < B_SZ; i += 1024) atomicAdd(&hist[cid[i]], 1);
  __syncthreads();
  if (tid < 64){
    int v = hist[tid];
    int x = v;
    #pragma unroll
    for (int d = 1; d < 64; d <<= 1){
      int y = __shfl_up(x, d, 64);
      if (tid >= d) x += y;
    }
    offsets[tid] = x - v;
    if (tid == 63) offsets[64] = x;
    hist[tid] = x - v;                  // reuse as cursor
  }
  __syncthreads();
  for (int i = tid; i < B_SZ; i += 1024){
    int c = cid[i];
    int p = atomicAdd(&hist[c], 1);
    bucket[p] = i;
    out[i] = b2[c];
  }
}

// Pack z into bucket-ordered bf16 rows: zp[slot][0..511]. ~4 MB, L2/L3-resident.
__global__ void k_zpack(const float* __restrict__ z, const int* __restrict__ bucket,
                        short* __restrict__ zp){
  int u = blockIdx.x * 256 + threadIdx.x;     // 262144 units of 8 elems
  int slot = u >> 6;
  int k0 = (u & 63) * 8;
  const float* src = z + (size_t)bucket[slot] * D_K + k0;
  float4 a = *(const float4*)src;
  float4 b = *(const float4*)(src + 4);
  s16x8 v;
  v[0]=f2bf(a.x); v[1]=f2bf(a.y); v[2]=f2bf(a.z); v[3]=f2bf(a.w);
  v[4]=f2bf(b.x); v[5]=f2bf(b.y); v[6]=f2bf(b.z); v[7]=f2bf(b.w);
  *(s16x8*)(zp + ((size_t)slot << 9) + k0) = v;
}

__global__ __launch_bounds__(256, 4) void k_main(
    const short* __restrict__ zp, const float* __restrict__ W1,
    const float* __restrict__ b1, const float* __restrict__ W2,
    const int* __restrict__ offsets, const int* __restrict__ bucket,
    float* __restrict__ out)
{
  __shared__ s16x8 A_lds[NT * 64];         // 32 KB: [ks][lane] frag-ordered bf16
  __shared__ float B_lds[2][BK * 128];     // 2 x 8 KB: [k][h] f32
  __shared__ float partial[ROWS];

  // bid = o*64 + c : company fixed per XCD (bid%8 = c%8); mc INNER so the
  // <=4 blocks re-reading the same (c,hs) W1 panel are consecutive -> L2-hit.
  const int bid = blockIdx.x;
  const int c = bid & 63;
  const int o = bid >> 6;                  // 0..31
  const int mc = o & 3, hs = o >> 2;       // 4 row-chunks x 8 h-slices
  const int off_c = offsets[c];
  const int n_c = offsets[c + 1] - off_c;
  const int rb = mc * ROWS;
  if (rb >= n_c) return;

  const int tid  = threadIdx.x;
  const int lane = tid & 63, wave = tid >> 6;    // 4 waves x 32 h
  const int l31 = lane & 31, lhi = lane >> 5;
  const int hcol = hs * 128 + wave * 32 + l31;   // h within company
  const float b1v = b1[c * H_N + hcol];
  const float w2v = W2[c * H_N + hcol];
  const float* Wpanel = W1 + (size_t)c * D_K * H_N + hs * 128;

  if (tid < ROWS) partial[tid] = 0.0f;

  // ---- B staging: one [16k x 128h] f32 tile via global_load_lds dwordx4 ----
  // thread tid covers f32 idx tid*4 and tid*4+4096 (k rows r0 and r0+8).
  const int r0 = tid >> 5;                 // 0..7
  const int hc = (tid & 31) * 4;
  auto stage = [&](int t, int buf){
    const float* src = Wpanel + (size_t)(t * BK + r0) * H_N + hc;
    float* dst = &B_lds[buf][r0 * 128 + hc];       // == wave-base + lane*16
    __builtin_amdgcn_global_load_lds(
      (const __attribute__((address_space(1))) void*)src,
      (__attribute__((address_space(3))) void*)dst, 16, 0, 0);
    __builtin_amdgcn_global_load_lds(
      (const __attribute__((address_space(1))) void*)(src + 8 * H_N),
      (__attribute__((address_space(3))) void*)(dst + 8 * 128), 16, 0, 0);
  };

  stage(0, 0);

  // ---- A staging: 32 rows x 512 k bf16 (zp is bf16 already), frag order ----
  #pragma unroll
  for (int j = 0; j < 8; ++j){
    int u = tid + 256 * j;                 // 0..2047
    int ks = u >> 6, lu = u & 63;
    int row = lu & 31, lh = lu >> 5;
    A_lds[u] = *(const s16x8*)(zp + ((size_t)(off_c + rb + row) << 9) + ks * BK + lh * 8);
  }
  __syncthreads();     // A visible; B tile 0 landed (vmcnt drain)

  f32x16 acc = 0;

  // ---- K loop: one barrier per tile; 3 blocks/CU hide the vmcnt drains ----
  for (int t = 0; t < NT; ++t){
    if (t + 1 < NT) stage(t + 1, (t + 1) & 1);
    const float* Bt = &B_lds[t & 1][0];
    s16x8 bf;
    #pragma unroll
    for (int e = 0; e < 8; ++e)
      bf[e] = f2bf(Bt[(lhi * 8 + e) * 128 + wave * 32 + l31]);
    s16x8 af = A_lds[t * 64 + lane];
    acc = __builtin_amdgcn_mfma_f32_32x32x16_bf16(af, bf, acc, 0, 0, 0);
    __syncthreads();
  }

  // ---- epilogue: GELU + W2 dot, 32-lane reduce, LDS partial, flush ----
  #pragma unroll
  for (int r = 0; r < 16; ++r){
    int r_loc = (r & 3) + 8 * (r >> 2) + 4 * lhi;
    float s = gelu_exact(acc[r] + b1v) * w2v;
    s += __shfl_xor(s, 1, 64);
    s += __shfl_xor(s, 2, 64);
    s += __shfl_xor(s, 4, 64);
    s += __shfl_xor(s, 8, 64);
    s += __shfl_xor(s, 16, 64);
    if (l31 == 0 && rb + r_loc < n_c)
      atomicAdd(&partial[r_loc], s);
  }
  __syncthreads();
  if (tid < ROWS){
    int g = rb + tid;
    if (g < n_c)
      atomicAdd(&out[bucket[off_c + g]], partial[tid]);
  }
}

extern "C" void kernel_launch(void* const* d_in, const int* in_sizes, int n_in,
                              void* d_out, int out_size, void* d_ws, size_t ws_size,
                              hipStream_t stream){
  const float* z  = (const float*)d_in[0];
  const int*   cid= (const int*)  d_in[1];
  const float* W1 = (const float*)d_in[2];
  const float* b1 = (const float*)d_in[3];
  const float* W2 = (const float*)d_in[4];
  const float* b2 = (const float*)d_in[5];
  float* out = (float*)d_out;

  int*   ws      = (int*)d_ws;
  int*   offsets = ws;                                   // [65]
  int*   bucket  = ws + 128;                             // [4096]
  short* zp      = (short*)((char*)d_ws + ZP_OFF_BYTES); // [ZP_ROWS*512] bf16

  k_prep <<<1, 1024, 0, stream>>>(cid, b2, offsets, bucket, out);
  k_zpack<<<1024, 256, 0, stream>>>(z, bucket, zp);
  k_main <<<C_N * 32, 256, 0, stream>>>(zp, W1, b1, W2, offsets, bucket, out);
}

// Round 9
// 52.710 us; speedup vs baseline: 1.2670x; 1.1680x over previous
//
#include <hip/hip_runtime.h>

typedef float f32x16 __attribute__((ext_vector_type(16)));
typedef short s16x8  __attribute__((ext_vector_type(8)));

#define B_SZ 4096
#define C_N  64
#define D_K  512
#define H_N  1024
#define BK   16                 // k per tile
#define NT   32                 // 512/16 tiles
#define ROWS 128                // rows per block pass (4 m-frags of 32)
#define ZP_OFF_BYTES 32768
#define ZP_ROWS (B_SZ + 128)    // pad: off_c+rb+127 <= 4223 < 4224

__device__ __forceinline__ short f2bf(float f){
  unsigned u = __float_as_uint(f);
  u += 0x7FFFu + ((u >> 16) & 1u);   // RTNE
  return (short)(u >> 16);
}
// A&S 7.1.26, |err| <= 1.5e-7
__device__ __forceinline__ float erf_fast(float x){
  float ax = fabsf(x);
  float t = __builtin_amdgcn_rcpf(1.0f + 0.3275911f * ax);
  float p = t * (0.254829592f + t * (-0.284496736f + t * (1.421413741f +
            t * (-1.453152027f + t * 1.061405429f))));
  float r = 1.0f - p * __expf(-ax * ax);
  return copysignf(r, x);
}
__device__ __forceinline__ float gelu_exact(float x){
  return 0.5f * x * (1.0f + erf_fast(x * 0.70710678118654752f));
}

// Fused count + scan + scatter + out-init. One block of 1024.
__global__ void k_prep(const int* __restrict__ cid, const float* __restrict__ b2,
                       int* __restrict__ offsets, int* __restrict__ bucket,
                       float* __restrict__ out){
  __shared__ int hist[C_N];
  const int tid = threadIdx.x;
  if (tid < C_N) hist[tid] = 0;
  __syncthreads();
  for (int i = tid; i < B_SZ; i += 1024) atomicAdd(&hist[cid[i]], 1);
  __syncthreads();
  if (tid < 64){
    int v = hist[tid];
    int x = v;
    #pragma unroll
    for (int d = 1; d < 64; d <<= 1){
      int y = __shfl_up(x, d, 64);
      if (tid >= d) x += y;
    }
    offsets[tid] = x - v;
    if (tid == 63) offsets[64] = x;
    hist[tid] = x - v;                  // reuse as cursor
  }
  __syncthreads();
  for (int i = tid; i < B_SZ; i += 1024){
    int c = cid[i];
    int p = atomicAdd(&hist[c], 1);
    bucket[p] = i;
    out[i] = b2[c];
  }
}

// Pack z into bucket-ordered bf16 rows: zp[slot][0..511]. ~4 MB, L2-resident.
__global__ void k_zpack(const float* __restrict__ z, const int* __restrict__ bucket,
                        short* __restrict__ zp){
  int u = blockIdx.x * 256 + threadIdx.x;     // 262144 units of 8 elems
  int slot = u >> 6;
  int k0 = (u & 63) * 8;
  const float* src = z + (size_t)bucket[slot] * D_K + k0;
  float4 a = *(const float4*)src;
  float4 b = *(const float4*)(src + 4);
  s16x8 v;
  v[0]=f2bf(a.x); v[1]=f2bf(a.y); v[2]=f2bf(a.z); v[3]=f2bf(a.w);
  v[4]=f2bf(b.x); v[5]=f2bf(b.y); v[6]=f2bf(b.z); v[7]=f2bf(b.w);
  *(s16x8*)(zp + ((size_t)slot << 9) + k0) = v;
}

__global__ __launch_bounds__(256, 2) void k_main(
    const short* __restrict__ zp, const float* __restrict__ W1,
    const float* __restrict__ b1, const float* __restrict__ W2,
    const int* __restrict__ offsets, const int* __restrict__ bucket,
    float* __restrict__ out)
{
  // 4-slot pipelined LDS: B slots [16k][128h] f32, A slots [128row][16k] bf16
  __shared__ float B_lds[4][BK * 128];     // 32 KB
  __shared__ char  A_lds[4][4096];         // 16 KB
  __shared__ float partial[ROWS];          // 512 B   (total 49664 B -> 2-3 blk/CU)

  // bid = hs*64 + c : bid%8 = c%8 -> one company per XCD (zp L2 locality);
  // the 8 hs-blocks of a company read DISJOINT W1 panels: W1 fetched once.
  const int bid = blockIdx.x;
  const int c = bid & 63, hs = bid >> 6;
  const int off_c = offsets[c];
  const int n_c = offsets[c + 1] - off_c;
  if (n_c == 0) return;

  const int tid  = threadIdx.x;
  const int lane = tid & 63, wave = tid >> 6;    // 4 waves x 32 h
  const int l31 = lane & 31, lhi = lane >> 5;
  const int hcol = hs * 128 + wave * 32 + l31;   // h within company
  const float b1v = b1[c * H_N + hcol];
  const float w2v = W2[c * H_N + hcol];
  const float* Wpanel = W1 + (size_t)c * D_K * H_N + hs * 128;

  // staging geometry (all thread-uniform: exactly 3 gload_lds per tile)
  const int r0 = tid >> 5;                 // B k-row 0..7
  const int hc = (tid & 31) * 4;           // B h-col (f32)
  const int arow = tid >> 1;               // A row 0..127
  const int akh  = (tid & 1) * 8;          // A k-half (bf16 elems)

  if (tid < ROWS) partial[tid] = 0.0f;

  for (int rb = 0; rb < n_c; rb += ROWS){
    const short* zrow = zp + ((size_t)(off_c + rb + arow) << 9) + akh;

    auto stage = [&](int t){
      const int s = t & 3;
      const float* bsrc = Wpanel + (size_t)(t * BK + r0) * H_N + hc;
      // B: dst byte offset r0*512 + hc*4 == tid*16 (linear, wave-uniform+lane*16)
      __builtin_amdgcn_global_load_lds(
        (const __attribute__((address_space(1))) void*)bsrc,
        (__attribute__((address_space(3))) void*)(&B_lds[s][r0 * 128 + hc]), 16, 0, 0);
      __builtin_amdgcn_global_load_lds(
        (const __attribute__((address_space(1))) void*)(bsrc + 8 * H_N),
        (__attribute__((address_space(3))) void*)(&B_lds[s][(r0 + 8) * 128 + hc]), 16, 0, 0);
      // A: dst byte offset arow*32 + akh*2 == tid*16 (linear)
      __builtin_amdgcn_global_load_lds(
        (const __attribute__((address_space(1))) void*)(zrow + t * BK),
        (__attribute__((address_space(3))) void*)(&A_lds[s][tid * 16]), 16, 0, 0);
    };

    stage(0); stage(1); stage(2);          // 9 loads in flight

    f32x16 acc[4];
    acc[0] = 0; acc[1] = 0; acc[2] = 0; acc[3] = 0;

    for (int t = 0; t < NT; ++t){
      if (t + 3 < NT) stage(t + 3);        // slot (t+3)&3 freed at end of t-1
      if      (t <  NT - 3) asm volatile("s_waitcnt vmcnt(9)" ::: "memory");
      else if (t == NT - 3) asm volatile("s_waitcnt vmcnt(6)" ::: "memory");
      else if (t == NT - 2) asm volatile("s_waitcnt vmcnt(3)" ::: "memory");
      else                  asm volatile("s_waitcnt vmcnt(0)" ::: "memory");
      __builtin_amdgcn_s_barrier();        // tile t fully in LDS for all waves

      const int s = t & 3;
      const float* Bt = &B_lds[s][0];
      s16x8 bf;
      #pragma unroll
      for (int e = 0; e < 8; ++e)
        bf[e] = f2bf(Bt[(lhi * 8 + e) * 128 + wave * 32 + l31]);
      const s16x8* At = (const s16x8*)&A_lds[s][0];
      #pragma unroll
      for (int m = 0; m < 4; ++m){
        s16x8 af = At[(m * 32 + l31) * 2 + lhi];
        acc[m] = __builtin_amdgcn_mfma_f32_32x32x16_bf16(af, bf, acc[m], 0, 0, 0);
      }
      __builtin_amdgcn_s_barrier();        // all waves done with slot s
    }

    // ---- epilogue: GELU + W2 dot, 32-lane reduce, LDS partial, flush ----
    #pragma unroll
    for (int m = 0; m < 4; ++m){
      #pragma unroll
      for (int r = 0; r < 16; ++r){
        int r_loc = m * 32 + (r & 3) + 8 * (r >> 2) + 4 * lhi;
        float v = gelu_exact(acc[m][r] + b1v) * w2v;
        v += __shfl_xor(v, 1, 64);
        v += __shfl_xor(v, 2, 64);
        v += __shfl_xor(v, 4, 64);
        v += __shfl_xor(v, 8, 64);
        v += __shfl_xor(v, 16, 64);
        if (l31 == 0 && rb + r_loc < n_c)
          atomicAdd(&partial[r_loc], v);
      }
    }
    __syncthreads();
    if (tid < ROWS){
      int g = rb + tid;
      if (g < n_c)
        atomicAdd(&out[bucket[off_c + g]], partial[tid]);
      partial[tid] = 0.0f;                 // re-init for next pass (rare)
    }
  }
}

extern "C" void kernel_launch(void* const* d_in, const int* in_sizes, int n_in,
                              void* d_out, int out_size, void* d_ws, size_t ws_size,
                              hipStream_t stream){
  const float* z  = (const float*)d_in[0];
  const int*   cid= (const int*)  d_in[1];
  const float* W1 = (const float*)d_in[2];
  const float* b1 = (const float*)d_in[3];
  const float* W2 = (const float*)d_in[4];
  const float* b2 = (const float*)d_in[5];
  float* out = (float*)d_out;

  int*   ws      = (int*)d_ws;
  int*   offsets = ws;                                   // [65]
  int*   bucket  = ws + 128;                             // [4096]
  short* zp      = (short*)((char*)d_ws + ZP_OFF_BYTES); // [ZP_ROWS*512] bf16

  k_prep <<<1, 1024, 0, stream>>>(cid, b2, offsets, bucket, out);
  k_zpack<<<1024, 256, 0, stream>>>(z, bucket, zp);
  k_main <<<C_N * 8, 256, 0, stream>>>(zp, W1, b1, W2, offsets, bucket, out);
}